// Round 2
// baseline (1087.306 us; speedup 1.0000x reference)
//
#include <hip/hip_runtime.h>

#define N 2048
#define QUADS (N * N / 4)   // float4 elements total = 1M
#define BLK 256
#define GRD (QUADS / BLK)   // 4096 blocks

// ---- init: x = exp(-50*((X-0.5)^2 + (Y-0.5)^2)) ----
__global__ __launch_bounds__(BLK) void jm_init(const float4* __restrict__ X,
                                               const float4* __restrict__ Y,
                                               float4* __restrict__ out) {
    int t = blockIdx.x * BLK + threadIdx.x;
    float4 x = X[t];
    float4 y = Y[t];
    float4 r;
    r.x = expf(-50.f * ((x.x - 0.5f) * (x.x - 0.5f) + (y.x - 0.5f) * (y.x - 0.5f)));
    r.y = expf(-50.f * ((x.y - 0.5f) * (x.y - 0.5f) + (y.y - 0.5f) * (y.y - 0.5f)));
    r.z = expf(-50.f * ((x.z - 0.5f) * (x.z - 0.5f) + (y.z - 0.5f) * (y.z - 0.5f)));
    r.w = expf(-50.f * ((x.w - 0.5f) * (x.w - 0.5f) + (y.w - 0.5f) * (y.w - 0.5f)));
    out[t] = r;
}

// ---- one Jacobi sweep: out = 0.25*(up+down+left+right), boundary = 0 ----
__global__ __launch_bounds__(BLK) void jm_step(const float* __restrict__ in,
                                               float* __restrict__ out) {
    int t = blockIdx.x * BLK + threadIdx.x;     // quad index
    int row = t >> 9;                           // N/4 = 512 quads per row
    int col = (t & 511) << 2;                   // leading element column

    float4* o = (float4*)(out + row * N + col);

    if (row == 0 || row == N - 1) {
        *o = make_float4(0.f, 0.f, 0.f, 0.f);
        return;
    }

    const float4 up = *(const float4*)(in + (row - 1) * N + col);
    const float4 dn = *(const float4*)(in + (row + 1) * N + col);
    const float4 c  = *(const float4*)(in + row * N + col);
    float left  = (col > 0)     ? in[row * N + col - 1] : 0.f;
    float right = (col + 4 < N) ? in[row * N + col + 4] : 0.f;

    float4 r;
    r.x = 0.25f * (up.x + dn.x + left + c.y);
    r.y = 0.25f * (up.y + dn.y + c.x  + c.z);
    r.z = 0.25f * (up.z + dn.z + c.y  + c.w);
    r.w = 0.25f * (up.w + dn.w + c.z  + right);

    if (col == 0)     r.x = 0.f;   // mask: left boundary column
    if (col + 4 == N) r.w = 0.f;   // mask: right boundary column

    *o = r;
}

extern "C" void kernel_launch(void* const* d_in, const int* in_sizes, int n_in,
                              void* d_out, int out_size, void* d_ws, size_t ws_size,
                              hipStream_t stream) {
    const float* X = (const float*)d_in[0];
    const float* Y = (const float*)d_in[1];

    float* a = (float*)d_out;   // ping
    float* b = (float*)d_ws;    // pong (needs 16 MiB of workspace)

    jm_init<<<GRD, BLK, 0, stream>>>((const float4*)X, (const float4*)Y, (float4*)a);

    for (int it = 0; it < 100; ++it) {
        jm_step<<<GRD, BLK, 0, stream>>>(a, b);
        float* t = a; a = b; b = t;
    }
    // 100 sweeps (even) -> final field is back in d_out
}

// Round 3
// 496.468 us; speedup vs baseline: 2.1901x; 2.1901x over previous
//
#include <hip/hip_runtime.h>

#define N     2048
#define TX    128             // output tile width
#define TY    64              // output tile height
#define HALO  10              // sweeps fused per launch
#define WX    (TX + 2*HALO)   // 148 window width (data cols)
#define WY    (TY + 2*HALO)   // 84  window rows
#define LSTR  156             // LDS row stride (words): 4 pad + 148 + 4 pad
#define COFF  4               // data col c -> lds col c+COFF (keeps float4 16B-aligned)
#define NTHR  512
#define QPR   (WX/4)          // 37 float4 quads per compute row
#define CROWS (WY-2)          // 82 compute rows (window rows 1..82)
#define NQ    (CROWS*QPR)     // 3034 compute quads
#define QITER ((NQ + NTHR - 1)/NTHR)     // 6
#define LWORDS (WY*LSTR)      // 13104 words = 52.4 KB LDS
#define LITER ((LWORDS + NTHR - 1)/NTHR) // 26
#define SQ    (TY*(TX/4))     // 2048 store quads
#define SITER (SQ/NTHR)       // 4

// ---- init: x = exp(-50*((X-0.5)^2 + (Y-0.5)^2)) ----
__global__ __launch_bounds__(256) void jm_init(const float4* __restrict__ X,
                                               const float4* __restrict__ Y,
                                               float4* __restrict__ out) {
    int t = blockIdx.x * 256 + threadIdx.x;
    float4 x = X[t];
    float4 y = Y[t];
    float4 r;
    r.x = expf(-50.f * ((x.x - 0.5f) * (x.x - 0.5f) + (y.x - 0.5f) * (y.x - 0.5f)));
    r.y = expf(-50.f * ((x.y - 0.5f) * (x.y - 0.5f) + (y.y - 0.5f) * (y.y - 0.5f)));
    r.z = expf(-50.f * ((x.z - 0.5f) * (x.z - 0.5f) + (y.z - 0.5f) * (y.z - 0.5f)));
    r.w = expf(-50.f * ((x.w - 0.5f) * (x.w - 0.5f) + (y.w - 0.5f) * (y.w - 0.5f)));
    out[t] = r;
}

// ---- fused: load window -> HALO Jacobi sweeps in LDS -> store tile ----
// Validity invariant: after s in-LDS sweeps, a window cell at edge-distance d
// holds the correct sweep-s value iff d >= s. Output tile cells have d >= HALO,
// so HALO sweeps are exact. Edge/junk cells never reach the output region.
__global__ __launch_bounds__(NTHR) void jm_fused(const float* __restrict__ in,
                                                 float* __restrict__ out) {
    __shared__ float lds[LWORDS];
    const int bx = blockIdx.x & 15;        // N/TX = 16
    const int by = blockIdx.x >> 4;        // N/TY = 32
    const int gx0 = bx * TX - HALO;
    const int gy0 = by * TY - HALO;
    const int t = threadIdx.x;

    // ---- load window (pads + out-of-domain -> 0) ----
    for (int i = 0; i < LITER; ++i) {
        int e = t + NTHR * i;
        if (e < LWORDS) {
            int r  = e / LSTR;
            int ac = e - r * LSTR;
            int wc = ac - COFF;
            int gr = gy0 + r;
            int gc = gx0 + wc;
            float v = 0.f;
            if (wc >= 0 && wc < WX && gr >= 0 && gr < N && gc >= 0 && gc < N)
                v = in[gr * N + gc];
            lds[e] = v;
        }
    }
    __syncthreads();

    // ---- HALO sweeps, register-staged (single LDS buffer) ----
    float4 vr[QITER];
    for (int s = 0; s < HALO; ++s) {
        #pragma unroll
        for (int i = 0; i < QITER; ++i) {
            int j = t + NTHR * i;
            if (j < NQ) {
                int wr = 1 + j / QPR;
                int q  = j - (wr - 1) * QPR;
                int base = wr * LSTR + COFF + 4 * q;
                float4 up = *(const float4*)&lds[base - LSTR];
                float4 dn = *(const float4*)&lds[base + LSTR];
                float4 ct = *(const float4*)&lds[base];
                float  lf = lds[base - 1];
                float  rg = lds[base + 4];
                float4 nv;
                nv.x = 0.25f * (up.x + dn.x + lf   + ct.y);
                nv.y = 0.25f * (up.y + dn.y + ct.x + ct.z);
                nv.z = 0.25f * (up.z + dn.z + ct.y + ct.w);
                nv.w = 0.25f * (up.w + dn.w + ct.z + rg);
                // Dirichlet mask: zero on/outside the global boundary ring
                int gr  = gy0 + wr;
                int gc0 = gx0 + 4 * q;
                bool rin = (gr >= 1) && (gr <= N - 2);
                nv.x = (rin && gc0     >= 1 && gc0     <= N - 2) ? nv.x : 0.f;
                nv.y = (rin && gc0 + 1 >= 1 && gc0 + 1 <= N - 2) ? nv.y : 0.f;
                nv.z = (rin && gc0 + 2 >= 1 && gc0 + 2 <= N - 2) ? nv.z : 0.f;
                nv.w = (rin && gc0 + 3 >= 1 && gc0 + 3 <= N - 2) ? nv.w : 0.f;
                vr[i] = nv;
            }
        }
        __syncthreads();
        #pragma unroll
        for (int i = 0; i < QITER; ++i) {
            int j = t + NTHR * i;
            if (j < NQ) {
                int wr = 1 + j / QPR;
                int q  = j - (wr - 1) * QPR;
                *(float4*)&lds[wr * LSTR + COFF + 4 * q] = vr[i];
            }
        }
        __syncthreads();
    }

    // ---- store 128x64 output tile ----
    for (int i = 0; i < SITER; ++i) {
        int j = t + NTHR * i;          // < 2048
        int r = j >> 5;                // row in tile (32 quads/row)
        int q = j & 31;
        int wr = HALO + r;
        int ac = COFF + HALO + 4 * q;  // 8B-aligned LDS offset -> two float2 reads
        float2 a = *(const float2*)&lds[wr * LSTR + ac];
        float2 b = *(const float2*)&lds[wr * LSTR + ac + 2];
        int gr = gy0 + wr;             // = by*TY + r
        int gc = gx0 + HALO + 4 * q;   // = bx*TX + 4q, 16B-aligned
        float4 o; o.x = a.x; o.y = a.y; o.z = b.x; o.w = b.y;
        *(float4*)&out[gr * N + gc] = o;
    }
}

extern "C" void kernel_launch(void* const* d_in, const int* in_sizes, int n_in,
                              void* d_out, int out_size, void* d_ws, size_t ws_size,
                              hipStream_t stream) {
    const float* X = (const float*)d_in[0];
    const float* Y = (const float*)d_in[1];

    float* a = (float*)d_out;   // ping
    float* b = (float*)d_ws;    // pong (16 MiB of workspace)

    jm_init<<<(N * N / 4) / 256, 256, 0, stream>>>((const float4*)X, (const float4*)Y,
                                                   (float4*)a);

    // 100 sweeps = 10 launches x 10 fused sweeps; even count -> ends in d_out
    for (int it = 0; it < 10; ++it) {
        jm_fused<<<(N / TX) * (N / TY), NTHR, 0, stream>>>(a, b);
        float* t = a; a = b; b = t;
    }
}

// Round 5
// 326.126 us; speedup vs baseline: 3.3340x; 1.5223x over previous
//
#include <hip/hip_runtime.h>

#define N      2048
#define HALO   10            // sweeps fused per launch
#define SWP    10
#define WX     128           // window width  = 32 quads (fits 32-lane shuffle bands)
#define QX     32
#define TX     108           // output tile width  = WX - 2*HALO
#define WY     64            // window rows
#define TY     44            // output tile height = WY - 2*HALO
#define NTX    19            // x tiles (last clamped to N-TX, overlap benign)
#define NTY    47            // y tiles (last clamped to N-TY)
#define LW     (WY*WX)       // 8192 words = 32 KB per buffer
#define NTHR   512

// ---- init: x = exp(-50*((X-0.5)^2 + (Y-0.5)^2)) ----
__global__ __launch_bounds__(256) void jm_init(const float4* __restrict__ X,
                                               const float4* __restrict__ Y,
                                               float4* __restrict__ out) {
    int t = blockIdx.x * 256 + threadIdx.x;
    float4 x = X[t];
    float4 y = Y[t];
    float4 r;
    r.x = expf(-50.f * ((x.x - 0.5f) * (x.x - 0.5f) + (y.x - 0.5f) * (y.x - 0.5f)));
    r.y = expf(-50.f * ((x.y - 0.5f) * (x.y - 0.5f) + (y.y - 0.5f) * (y.y - 0.5f)));
    r.z = expf(-50.f * ((x.z - 0.5f) * (x.z - 0.5f) + (y.z - 0.5f) * (y.z - 0.5f)));
    r.w = expf(-50.f * ((x.w - 0.5f) * (x.w - 0.5f) + (y.w - 0.5f) * (y.w - 0.5f)));
    out[t] = r;
}

// Fused 10 sweeps. Ping-pong LDS; 16 bands x 32 quad-cols; vertical register
// rolling (up/ct/dn); lf/rg via 32-wide shuffles. Validity: contamination
// (stale edges, junk in unwritten pong rows 0/63) advances 1 cell/sweep (L1),
// so stored cells at window distance >= HALO are exact after HALO sweeps.
__global__ __launch_bounds__(NTHR) void jm_sweep(const float* __restrict__ in,
                                                 float* __restrict__ out) {
    __shared__ float lds[2 * LW];
    const int bx = blockIdx.x % NTX;
    const int by = blockIdx.x / NTX;
    const int ox = (bx < NTX - 1) ? bx * TX : (N - TX);
    const int oy = (by < NTY - 1) ? by * TY : (N - TY);
    const int gx0 = ox - HALO;
    const int gy0 = oy - HALO;
    const int t = threadIdx.x;

    // ---- load window -> buffer 0 (out-of-domain -> 0) ----
    #pragma unroll
    for (int i = 0; i < LW / NTHR; ++i) {      // 16 iters, exact
        int e = t + NTHR * i;
        int r = e >> 7, c = e & 127;
        int gr = gy0 + r, gc = gx0 + c;
        float v = 0.f;
        if (gr >= 0 && gr < N && gc >= 0 && gc < N) v = in[gr * N + gc];
        lds[e] = v;
    }
    __syncthreads();

    const int g = t >> 5;                      // band 0..15
    const int c = t & 31;                      // quad column
    // 62 compute rows (1..62): bands 0..13 -> 4 rows, bands 14,15 -> 3 rows
    const int nr = (g < 14) ? 4 : 3;
    const int r0 = (g < 14) ? (1 + 4 * g) : (57 + 3 * (g - 14));
    const int gc0 = gx0 + 4 * c;
    // column mask factors: 0.25 if global col interior, else 0 (exact pow2 mul)
    const float q0 = (gc0     >= 1 && gc0     <= N - 2) ? 0.25f : 0.f;
    const float q1 = (gc0 + 1 >= 1 && gc0 + 1 <= N - 2) ? 0.25f : 0.f;
    const float q2 = (gc0 + 2 >= 1 && gc0 + 2 <= N - 2) ? 0.25f : 0.f;
    const float q3 = (gc0 + 3 >= 1 && gc0 + 3 <= N - 2) ? 0.25f : 0.f;

    for (int s = 0; s < SWP; ++s) {
        const float4* orow = (const float4*)(lds + (s & 1) * LW);
        float4*       nrow = (float4*)(lds + ((s & 1) ^ 1) * LW);
        float4 up = orow[(r0 - 1) * QX + c];
        float4 ct = orow[ r0      * QX + c];
        #pragma unroll
        for (int k = 0; k < 4; ++k) {
            if (k < nr) {                       // wave-uniform (band pairs match)
                int r = r0 + k;
                float4 dn = orow[(r + 1) * QX + c];
                float lfv = __shfl_up(ct.w, 1, 32);
                float rgv = __shfl_down(ct.x, 1, 32);
                float lf = (c == 0)  ? 0.f : lfv;
                float rg = (c == 31) ? 0.f : rgv;
                int grow = gy0 + r;
                float rs = (grow >= 1 && grow <= N - 2) ? 1.f : 0.f;
                float4 nv;
                nv.x = (up.x + dn.x + lf   + ct.y) * (q0 * rs);
                nv.y = (up.y + dn.y + ct.x + ct.z) * (q1 * rs);
                nv.z = (up.z + dn.z + ct.y + ct.w) * (q2 * rs);
                nv.w = (up.w + dn.w + ct.z + rg  ) * (q3 * rs);
                nrow[r * QX + c] = nv;
                up = ct; ct = dn;
            }
        }
        __syncthreads();
    }

    // ---- store tile: buffer 0 (SWP even), window rows 10..53, cols 10..117 ----
    #pragma unroll
    for (int i = 0; i < 5; ++i) {
        int j = t + NTHR * i;
        if (j < TY * (TX / 2)) {               // 2376 float2 stores
            int r = j / (TX / 2), p = j - (TX / 2) * r;
            float2 v = *(const float2*)&lds[(HALO + r) * WX + HALO + 2 * p];
            *(float2*)&out[(oy + r) * N + ox + 2 * p] = v;
        }
    }
}

extern "C" void kernel_launch(void* const* d_in, const int* in_sizes, int n_in,
                              void* d_out, int out_size, void* d_ws, size_t ws_size,
                              hipStream_t stream) {
    const float* X = (const float*)d_in[0];
    const float* Y = (const float*)d_in[1];

    float* a = (float*)d_out;   // ping
    float* b = (float*)d_ws;    // pong (16 MiB of workspace)

    jm_init<<<(N * N / 4) / 256, 256, 0, stream>>>((const float4*)X, (const float4*)Y,
                                                   (float4*)a);

    // 100 sweeps = 10 launches x 10 fused sweeps; even -> final lands in d_out
    for (int it = 0; it < 10; ++it) {
        jm_sweep<<<NTX * NTY, NTHR, 0, stream>>>(a, b);
        float* tp = a; a = b; b = tp;
    }
}

// Round 7
// 263.282 us; speedup vs baseline: 4.1298x; 1.2387x over previous
//
#include <hip/hip_runtime.h>

#define N      2048
#define HALO   10            // sweeps fused per launch
#define SWP    10
#define WX     128           // window width (16 threads x 8 cols)
#define WY     64            // window rows  (16 bands x 4 rows)
#define TX     108           // output tile width
#define TY     44            // output tile height
#define NTX    19            // last tile clamped; overlap writes identical values
#define NTY    47
#define NTHR   256
#define NB     16            // bands of 4 rows
#define PS     132           // LDS boundary row stride (words)

// ---- init: x = exp(-50*((X-0.5)^2 + (Y-0.5)^2)) ----
__global__ __launch_bounds__(256) void jm_init(const float4* __restrict__ X,
                                               const float4* __restrict__ Y,
                                               float4* __restrict__ out) {
    int t = blockIdx.x * 256 + threadIdx.x;
    float4 x = X[t];
    float4 y = Y[t];
    float4 r;
    r.x = expf(-50.f * ((x.x - 0.5f) * (x.x - 0.5f) + (y.x - 0.5f) * (y.x - 0.5f)));
    r.y = expf(-50.f * ((x.y - 0.5f) * (x.y - 0.5f) + (y.y - 0.5f) * (y.y - 0.5f)));
    r.z = expf(-50.f * ((x.z - 0.5f) * (x.z - 0.5f) + (y.z - 0.5f) * (y.z - 0.5f)));
    r.w = expf(-50.f * ((x.w - 0.5f) * (x.w - 0.5f) + (y.w - 0.5f) * (y.w - 0.5f)));
    out[t] = r;
}

// Register-resident fused sweeps: each thread owns a 4x8 patch in VGPRs.
// LDS holds only band-boundary rows (old top/bottom of each band per sweep).
// lf/rg neighbors via wave shuffles. Contamination advances 1 cell/sweep,
// stored cells sit at window distance >= HALO -> exact after HALO sweeps.
__global__ __launch_bounds__(NTHR) void jm_sweep(const float* __restrict__ in,
                                                 float* __restrict__ out) {
    __shared__ float bnd[2 * NB * PS];   // rows [0..15]=bbot(g), [16..31]=btop(g)
    const int bx = blockIdx.x % NTX;
    const int by = blockIdx.x / NTX;
    const int ox = (bx < NTX - 1) ? bx * TX : (N - TX);
    const int oy = (by < NTY - 1) ? by * TY : (N - TY);
    const int gx0 = ox - HALO, gy0 = oy - HALO;
    const int t = threadIdx.x;
    const int c = t & 15;                // column chunk (8 cols)
    const int g = t >> 4;                // band
    const int colb = gx0 + 8 * c;        // global col of patch col 0

    // column mask factors (0.25 interior, 0 on/outside boundary) and row masks
    float f[8];
    #pragma unroll
    for (int j = 0; j < 8; ++j)
        f[j] = (colb + j >= 1 && colb + j <= N - 2) ? 0.25f : 0.f;
    float rm[4];
    #pragma unroll
    for (int k = 0; k < 4; ++k) {
        int gr = gy0 + 4 * g + k;
        rm[k] = (gr >= 1 && gr <= N - 2) ? 1.f : 0.f;
    }

    // ---- load 4x8 patch (out-of-domain -> 0) ----
    float4 pA[4], pB[4];
    #pragma unroll
    for (int k = 0; k < 4; ++k) {
        int gr = gy0 + 4 * g + k;
        float4 a = make_float4(0.f, 0.f, 0.f, 0.f);
        float4 b = make_float4(0.f, 0.f, 0.f, 0.f);
        if (gr >= 0 && gr < N) {
            const float* row = in + (long)gr * N;
            if (colb >= 0 && colb + 7 < N) {
                a = *(const float4*)(row + colb);
                b = *(const float4*)(row + colb + 4);
            } else {
                float v[8];
                #pragma unroll
                for (int j = 0; j < 8; ++j)
                    v[j] = (colb + j >= 0 && colb + j < N) ? row[colb + j] : 0.f;
                a = make_float4(v[0], v[1], v[2], v[3]);
                b = make_float4(v[4], v[5], v[6], v[7]);
            }
        }
        pA[k] = a; pB[k] = b;
    }

    float* wrTop = &bnd[(NB + g) * PS + 8 * c];
    float* wrBot = &bnd[g * PS + 8 * c];
    const float* rdUp = &bnd[((g > 0) ? (g - 1) : 0) * PS + 8 * c];        // bbot[g-1]
    const float* rdDn = &bnd[(NB + ((g < NB - 1) ? (g + 1) : g)) * PS + 8 * c]; // btop[g+1]

    for (int s = 0; s < SWP; ++s) {
        // publish old boundary rows
        *(float4*)(wrTop)     = pA[0];
        *(float4*)(wrTop + 4) = pB[0];
        *(float4*)(wrBot)     = pA[3];
        *(float4*)(wrBot + 4) = pB[3];
        __syncthreads();
        float4 upA = make_float4(0.f, 0.f, 0.f, 0.f), upB = upA;
        float4 dnA = upA, dnB = upA;
        if (g > 0)      { upA = *(const float4*)rdUp; upB = *(const float4*)(rdUp + 4); }
        if (g < NB - 1) { dnA = *(const float4*)rdDn; dnB = *(const float4*)(rdDn + 4); }
        __syncthreads();   // reads done; next sweep may overwrite bnd

        float4 poA = upA, poB = upB;  // old row above current row
        #pragma unroll
        for (int k = 0; k < 4; ++k) {
            float4 cA = pA[k], cB = pB[k];
            float4 dA = (k < 3) ? pA[k + 1] : dnA;   // still old values
            float4 dB = (k < 3) ? pB[k + 1] : dnB;
            float lf = __shfl_up(cB.w, 1);
            float rg = __shfl_down(cA.x, 1);
            lf = (c == 0)  ? 0.f : lf;
            rg = (c == 15) ? 0.f : rg;
            float r = rm[k];
            float4 nA, nB;
            nA.x = (poA.x + dA.x + lf   + cA.y) * (f[0] * r);
            nA.y = (poA.y + dA.y + cA.x + cA.z) * (f[1] * r);
            nA.z = (poA.z + dA.z + cA.y + cA.w) * (f[2] * r);
            nA.w = (poA.w + dA.w + cA.z + cB.x) * (f[3] * r);
            nB.x = (poB.x + dB.x + cA.w + cB.y) * (f[4] * r);
            nB.y = (poB.y + dB.y + cB.x + cB.z) * (f[5] * r);
            nB.z = (poB.z + dB.z + cB.y + cB.w) * (f[6] * r);
            nB.w = (poB.w + dB.w + cB.z + rg  ) * (f[7] * r);
            pA[k] = nA; pB[k] = nB;
            poA = cA; poB = cB;
        }
    }

    // ---- store valid interior: window rows 10..53, cols 10..117 ----
    #pragma unroll
    for (int k = 0; k < 4; ++k) {
        int w = 4 * g + k;
        if (w >= HALO && w < WY - HALO) {
            float* orow = out + (long)(gy0 + w) * N;
            if (c >= 2 && c <= 13) {
                *(float4*)(orow + colb)     = pA[k];
                *(float4*)(orow + colb + 4) = pB[k];
            } else if (c == 1) {          // cols 8..15 -> keep 10..15
                float2 v; v.x = pA[k].z; v.y = pA[k].w;
                *(float2*)(orow + gx0 + 10) = v;
                *(float4*)(orow + gx0 + 12) = pB[k];
            } else if (c == 14) {         // cols 112..119 -> keep 112..117
                *(float4*)(orow + colb) = pA[k];
                float2 v; v.x = pB[k].x; v.y = pB[k].y;
                *(float2*)(orow + gx0 + 116) = v;
            }
        }
    }
}

extern "C" void kernel_launch(void* const* d_in, const int* in_sizes, int n_in,
                              void* d_out, int out_size, void* d_ws, size_t ws_size,
                              hipStream_t stream) {
    const float* X = (const float*)d_in[0];
    const float* Y = (const float*)d_in[1];

    float* a = (float*)d_out;   // ping
    float* b = (float*)d_ws;    // pong (16 MiB of workspace)

    jm_init<<<(N * N / 4) / 256, 256, 0, stream>>>((const float4*)X, (const float4*)Y,
                                                   (float4*)a);

    // 100 sweeps = 10 launches x 10 fused sweeps; even -> final lands in d_out
    for (int it = 0; it < 10; ++it) {
        jm_sweep<<<NTX * NTY, NTHR, 0, stream>>>(a, b);
        float* tp = a; a = b; b = tp;
    }
}